// Round 7
// baseline (160.929 us; speedup 1.0000x reference)
//
#include <hip/hip_runtime.h>
#include <cstdint>
#include <cstddef>

// Problem sizes (fixed by the reference)
#define MDIM 16384   // N_INPUT
#define CDIM 4096    // NUM_CENTERS
#define DDIM 256     // DIM
#define KDIM 512     // folded K (elements == fp8 bytes)

typedef float f32x4  __attribute__((ext_vector_type(4)));
typedef int   i32x4v __attribute__((ext_vector_type(4)));
typedef int   i32x8v __attribute__((ext_vector_type(8)));

// ---------------------------------------------------------------------------
// Fused prep (fp8 e4m3 via HW packed cvt):
//  blocks [0,4096):    A'[n][d] = x, A'[n][256+d] = x^2 ; zero score
//  blocks [4096,5120): inv = 1/(2 s^2); B'[c][d] = -2*c*inv; B'[c][256+d]=inv
//                      constc[c] = sum_d c^2*inv (fp32, one wave per center)
// ---------------------------------------------------------------------------
__global__ __launch_bounds__(256) void prep(
    const float* __restrict__ x, const float* __restrict__ centers,
    const float* __restrict__ sigmas,
    unsigned char* __restrict__ Ap, unsigned char* __restrict__ Bp,
    float* __restrict__ constc, float* __restrict__ score) {
    int b = blockIdx.x, tid = threadIdx.x;
    if (b < 4096) {
        int idx4 = b * 256 + tid;                 // over MDIM*DDIM/4
        float4 v = ((const float4*)x)[idx4];
        int n = idx4 >> 6, dq = idx4 & 63;
        int p0 = __builtin_amdgcn_cvt_pk_fp8_f32(v.x, v.y, 0, false);
        p0     = __builtin_amdgcn_cvt_pk_fp8_f32(v.z, v.w, p0, true);
        int p1 = __builtin_amdgcn_cvt_pk_fp8_f32(v.x * v.x, v.y * v.y, 0, false);
        p1     = __builtin_amdgcn_cvt_pk_fp8_f32(v.z * v.z, v.w * v.w, p1, true);
        *(int*)(Ap + (size_t)n * KDIM + dq * 4)        = p0;
        *(int*)(Ap + (size_t)n * KDIM + DDIM + dq * 4) = p1;
        if (idx4 < MDIM) score[idx4] = 0.0f;
    } else {
        int gid = (b - 4096) * 256 + tid;         // over CDIM*DDIM/4
        int c = gid >> 6, q = gid & 63;
        float4 cv = ((const float4*)centers)[gid];
        float4 sv = ((const float4*)sigmas)[gid];
        float ix = 1.0f / (2.0f * sv.x * sv.x);
        float iy = 1.0f / (2.0f * sv.y * sv.y);
        float iz = 1.0f / (2.0f * sv.z * sv.z);
        float iw = 1.0f / (2.0f * sv.w * sv.w);
        int p0 = __builtin_amdgcn_cvt_pk_fp8_f32(-2.0f * cv.x * ix, -2.0f * cv.y * iy, 0, false);
        p0     = __builtin_amdgcn_cvt_pk_fp8_f32(-2.0f * cv.z * iz, -2.0f * cv.w * iw, p0, true);
        int p1 = __builtin_amdgcn_cvt_pk_fp8_f32(ix, iy, 0, false);
        p1     = __builtin_amdgcn_cvt_pk_fp8_f32(iz, iw, p1, true);
        *(int*)(Bp + (size_t)c * KDIM + q * 4)        = p0;
        *(int*)(Bp + (size_t)c * KDIM + DDIM + q * 4) = p1;
        float t = cv.x * cv.x * ix + cv.y * cv.y * iy
                + cv.z * cv.z * iz + cv.w * cv.w * iw;
        #pragma unroll
        for (int m = 32; m; m >>= 1) t += __shfl_down(t, m, 64);
        if ((tid & 63) == 0) constc[c] = t;       // one wave == one center
    }
}

// ---------------------------------------------------------------------------
// Fused MX-fp8 GEMM + exp + weighted C-reduction.
// d2 = A' B'^T + constc ; score[m] += sum_n exp(-d2[m][n]) * w[n]
// R6: 512 threads (8 waves), 256x128 tile, BK=128. Each wave: 32 M-rows x
// 128 N-cols -> acc 2x8 f32x4 (64 regs), af[2] long-lived, bf per-j.
// launch_bounds(512,4): 4 waves/SIMD = 2 blocks/CU, 128-reg budget,
// live ~120 -> no spill (sentinel: WRITE_SIZE). 16 waves/CU hides the
// barrier drain that capped R5 at 8 waves/CU.
// XOR swizzle (R3-proven): 16B chunk g of row r at slot g^(r&7).
// ---------------------------------------------------------------------------
__global__ __launch_bounds__(512, 4) void gemm_fused(
    const unsigned char* __restrict__ A, const unsigned char* __restrict__ B,
    const float* __restrict__ constc, const float* __restrict__ w,
    float* __restrict__ score) {

    __shared__ unsigned char As[256 * 128];   // 32 KB
    __shared__ unsigned char Bs[128 * 128];   // 16 KB

    const int tid  = threadIdx.x;
    const int wave = tid >> 6;       // 0..7
    const int lane = tid & 63;
    const int quad = lane >> 4;      // 0..3
    const int l16  = lane & 15;

    const int bm = blockIdx.y;       // 0..63   (M blocks of 256)
    const int bn = blockIdx.x;       // 0..31   (C blocks of 128)

    const int wave_m = wave * 32;    // wave's 32 M-rows

    f32x4 acc[2][8] = {};

    // staging: one global_load_lds(16B)/lane/instr stages 1KB/wave
    // = 8 rows x 128 B. lane -> row (lane>>3), slot (lane&7); fetch the
    // XOR-swizzled global chunk so slot s of row r holds chunk s^(r&7).
    const int st_row = lane >> 3;                     // 0..7
    const int st_k   = ((lane & 7) ^ st_row) * 16;    // swizzled global byte off

    const unsigned char* Abase = A + (size_t)(bm * 256) * KDIM;
    const unsigned char* Bbase = B + (size_t)(bn * 128) * KDIM;

    // fragment read slots: lane (l16,quad) needs 16B chunks 2q, 2q+1 of its
    // row, each at XOR-swizzled slot (c ^ (l16&7)).
    const int rsw = l16 & 7;
    const int s0  = ((2 * quad)     ^ rsw) * 16;
    const int s1  = ((2 * quad + 1) ^ rsw) * 16;

    for (int k0 = 0; k0 < KDIM; k0 += 128) {
        #pragma unroll
        for (int c = 0; c < 4; ++c) {             // A: 32 slabs of 8 rows
            int slab = wave * 4 + c;              // 0..31
            const unsigned char* ga = Abase + (size_t)(slab * 8 + st_row) * KDIM + k0 + st_k;
            __builtin_amdgcn_global_load_lds(
                (const __attribute__((address_space(1))) void*)ga,
                (__attribute__((address_space(3))) void*)(As + slab * 1024), 16, 0, 0);
        }
        #pragma unroll
        for (int c = 0; c < 2; ++c) {             // B: 16 slabs of 8 rows
            int slab = wave * 2 + c;              // 0..15
            const unsigned char* gb = Bbase + (size_t)(slab * 8 + st_row) * KDIM + k0 + st_k;
            __builtin_amdgcn_global_load_lds(
                (const __attribute__((address_space(1))) void*)gb,
                (__attribute__((address_space(3))) void*)(Bs + slab * 1024), 16, 0, 0);
        }
        __syncthreads();

        i32x8v af[2];
        #pragma unroll
        for (int i = 0; i < 2; ++i) {
            const unsigned char* pa = As + (wave_m + i * 16 + l16) * 128;
            i32x4v* h = (i32x4v*)&af[i];
            h[0] = *(const i32x4v*)(pa + s0);
            h[1] = *(const i32x4v*)(pa + s1);
        }
        #pragma unroll
        for (int j = 0; j < 8; ++j) {
            const unsigned char* pb = Bs + (j * 16 + l16) * 128;
            i32x8v bf;
            i32x4v* h = (i32x4v*)&bf;
            h[0] = *(const i32x4v*)(pb + s0);
            h[1] = *(const i32x4v*)(pb + s1);
            #pragma unroll
            for (int i = 0; i < 2; ++i)
                acc[i][j] = __builtin_amdgcn_mfma_scale_f32_16x16x128_f8f6f4(
                    af[i], bf, acc[i][j],
                    0 /*cbsz: fp8 e4m3*/, 0 /*blgp: fp8 e4m3*/,
                    0, 0x7F7F7F7F /*scale A = 1.0*/,
                    0, 0x7F7F7F7F /*scale B = 1.0*/);
        }
        __syncthreads();
    }

    // Epilogue: d2 -> exp -> *w -> reduce over this tile's 128 columns.
    // C/D layout (16x16 shapes): col = l16 (=n), row = quad*4 + reg (=m).
    float rowsum[2][4];
    #pragma unroll
    for (int i = 0; i < 2; ++i)
        #pragma unroll
        for (int r = 0; r < 4; ++r) rowsum[i][r] = 0.0f;

    const float NEG_LOG2E = -1.4426950408889634f;
    #pragma unroll
    for (int j = 0; j < 8; ++j) {
        int ng = bn * 128 + j * 16 + l16;
        float wj = w[ng];
        float cj = constc[ng];
        #pragma unroll
        for (int i = 0; i < 2; ++i)
            #pragma unroll
            for (int r = 0; r < 4; ++r) {
                float d2 = acc[i][j][r] + cj;
                rowsum[i][r] += exp2f(NEG_LOG2E * d2) * wj;
            }
    }

    #pragma unroll
    for (int mask = 1; mask < 16; mask <<= 1)
        #pragma unroll
        for (int i = 0; i < 2; ++i)
            #pragma unroll
            for (int r = 0; r < 4; ++r)
                rowsum[i][r] += __shfl_xor(rowsum[i][r], mask, 64);

    if (l16 == 0) {
        #pragma unroll
        for (int i = 0; i < 2; ++i)
            #pragma unroll
            for (int r = 0; r < 4; ++r) {
                int mg = bm * 256 + wave_m + i * 16 + quad * 4 + r;
                atomicAdd(&score[mg], rowsum[i][r]);
            }
    }
}

// ---------------------------------------------------------------------------
// finalize: out[n] = sigmoid(score[n] + b)
// ---------------------------------------------------------------------------
__global__ void finalize(const float* __restrict__ score,
                         const float* __restrict__ b,
                         float* __restrict__ out) {
    int n = blockIdx.x * 256 + threadIdx.x;
    if (n < MDIM) {
        float s = score[n] + b[0];
        out[n] = 1.0f / (1.0f + exp2f(-1.4426950408889634f * s));
    }
}

extern "C" void kernel_launch(void* const* d_in, const int* in_sizes, int n_in,
                              void* d_out, int out_size, void* d_ws, size_t ws_size,
                              hipStream_t stream) {
    const float* x       = (const float*)d_in[0];
    const float* centers = (const float*)d_in[1];
    const float* sigmas  = (const float*)d_in[2];
    const float* w_lin   = (const float*)d_in[3];
    const float* b_lin   = (const float*)d_in[4];
    float* out = (float*)d_out;

    char* ws = (char*)d_ws;
    unsigned char* Ap = (unsigned char*)ws;                         // 8 MB
    unsigned char* Bp = (unsigned char*)(ws + (size_t)MDIM * KDIM); // 2 MB
    float* cc    = (float*)(ws + (size_t)MDIM * KDIM + (size_t)CDIM * KDIM); // 16 KB
    float* score = (float*)((char*)cc + CDIM * sizeof(float));      // 64 KB

    prep<<<dim3(4096 + 1024), dim3(256), 0, stream>>>(
        x, centers, sigmas, Ap, Bp, cc, score);
    gemm_fused<<<dim3(CDIM / 128, MDIM / 256), dim3(512), 0, stream>>>(
        Ap, Bp, cc, w_lin, score);
    finalize<<<dim3((MDIM + 255) / 256), dim3(256), 0, stream>>>(score, b_lin, out);
}

// Round 8
// 120.742 us; speedup vs baseline: 1.3328x; 1.3328x over previous
//
#include <hip/hip_runtime.h>
#include <cstdint>
#include <cstddef>

// Problem sizes (fixed by the reference)
#define MDIM 16384   // N_INPUT
#define CDIM 4096    // NUM_CENTERS
#define DDIM 256     // DIM
#define KDIM 512     // folded K elements; fp4 -> 256 bytes per row
#define KB   256     // row bytes (fp4)

typedef float f32x4  __attribute__((ext_vector_type(4)));
typedef int   i32x4v __attribute__((ext_vector_type(4)));
typedef int   i32x8v __attribute__((ext_vector_type(8)));

// e2m1 (OCP MXFP4) quantize, round-to-nearest: grid {0,.5,1,1.5,2,3,4,6}
__device__ __forceinline__ unsigned q4(float v) {
    unsigned s = (__builtin_bit_cast(unsigned, v) >> 31) << 3;
    float a = fabsf(v);
    unsigned c = (unsigned)(a >= 0.25f) + (a >= 0.75f) + (a >= 1.25f)
               + (a >= 1.75f) + (a >= 2.5f) + (a >= 3.5f) + (a >= 5.0f);
    return s | c;
}
__device__ __forceinline__ unsigned pack8(const float* v) {  // 8 vals -> 8 nibbles
    unsigned w = 0;
    #pragma unroll
    for (int i = 0; i < 8; ++i) w |= q4(v[i]) << (4 * i);
    return w;
}

// ---------------------------------------------------------------------------
// prep (fp4): A'[n] = [ x (256 fp4) | x^2/8 (256 fp4) ]       row = 256 B
//             B'[c] = [ -2*c*inv (256 fp4) | inv*8 (256 fp4) ]
//             constc[c] = sum_d c^2*inv (fp32).  Scales undone by MFMA E8M0.
//  blocks [0,2048): A-part, 8 elems/thread; also zeros score
//  blocks [2048,2560): B-part, 8 elems/thread, 32 threads/center
// ---------------------------------------------------------------------------
__global__ __launch_bounds__(256) void prep(
    const float* __restrict__ x, const float* __restrict__ centers,
    const float* __restrict__ sigmas,
    unsigned char* __restrict__ Ap, unsigned char* __restrict__ Bp,
    float* __restrict__ constc, float* __restrict__ score) {
    int b = blockIdx.x, tid = threadIdx.x;
    if (b < 2048) {
        int idx8 = b * 256 + tid;                 // over MDIM*DDIM/8
        int n = idx8 >> 5, d8 = idx8 & 31;
        float v[8], v2[8];
        *(float4*)(v)     = ((const float4*)x)[idx8 * 2];
        *(float4*)(v + 4) = ((const float4*)x)[idx8 * 2 + 1];
        #pragma unroll
        for (int i = 0; i < 8; ++i) v2[i] = v[i] * v[i] * 0.125f;  // x^2/8
        *(unsigned*)(Ap + (size_t)n * KB + d8 * 4)       = pack8(v);
        *(unsigned*)(Ap + (size_t)n * KB + 128 + d8 * 4) = pack8(v2);
        if (idx8 < MDIM) score[idx8] = 0.0f;
    } else {
        int gid8 = (b - 2048) * 256 + tid;        // over CDIM*DDIM/8
        int c = gid8 >> 5, d8 = gid8 & 31;
        float cv[8], sv[8], cr[8], iv[8];
        *(float4*)(cv)     = ((const float4*)centers)[gid8 * 2];
        *(float4*)(cv + 4) = ((const float4*)centers)[gid8 * 2 + 1];
        *(float4*)(sv)     = ((const float4*)sigmas)[gid8 * 2];
        *(float4*)(sv + 4) = ((const float4*)sigmas)[gid8 * 2 + 1];
        float t = 0.0f;
        #pragma unroll
        for (int i = 0; i < 8; ++i) {
            float inv = 1.0f / (2.0f * sv[i] * sv[i]);
            cr[i] = -2.0f * cv[i] * inv;
            iv[i] = inv * 8.0f;                   // inv*8 (undone by 2^-3)
            t += cv[i] * cv[i] * inv;
        }
        *(unsigned*)(Bp + (size_t)c * KB + d8 * 4)       = pack8(cr);
        *(unsigned*)(Bp + (size_t)c * KB + 128 + d8 * 4) = pack8(iv);
        #pragma unroll
        for (int m = 16; m; m >>= 1) t += __shfl_xor(t, m, 64);  // 32-lane groups
        if ((tid & 31) == 0) constc[c] = t;
    }
}

// ---------------------------------------------------------------------------
// Fused MX-fp4 GEMM + exp + weighted C-reduction.
// d2 = A' B'^T + constc ; score[m] += sum_n exp(-d2[m][n]) * w[n]
// R7: R5 skeleton exactly (256x128 tile, 4 waves of 64Mx128N, 48 KB LDS,
// (256,2), XOR swizzle, 12 staging instr/lane/round) but fp4 FMT:
// BK=256 elems = 128 B/row -> 2 K-rounds instead of 4; cbsz=blgp=4;
// per-round E8M0 scales: round0 (x * cross) = 1*1; round1 (x^2 * inv) =
// 2^3 * 2^-3 (prep pre-divided/multiplied by 8).
// ---------------------------------------------------------------------------
__global__ __launch_bounds__(256, 2) void gemm_fused(
    const unsigned char* __restrict__ A, const unsigned char* __restrict__ B,
    const float* __restrict__ constc, const float* __restrict__ w,
    float* __restrict__ score) {

    __shared__ unsigned char As[256 * 128];   // 32 KB
    __shared__ unsigned char Bs[128 * 128];   // 16 KB

    const int tid  = threadIdx.x;
    const int wave = tid >> 6;
    const int lane = tid & 63;
    const int quad = lane >> 4;      // 0..3
    const int l16  = lane & 15;

    const int bm = blockIdx.y;       // 0..63   (M blocks of 256)
    const int bn = blockIdx.x;       // 0..31   (C blocks of 128)

    const int wave_m = wave * 64;    // wave's 64 M-rows

    f32x4 acc[4][8] = {};

    // staging: one global_load_lds(16B)/lane stages 1024 B = 8 rows x 128 B.
    // lane -> row (lane>>3), slot (lane&7); fetch XOR-swizzled global chunk.
    const int st_row = lane >> 3;                     // 0..7
    const int st_k   = ((lane & 7) ^ st_row) * 16;    // swizzled global byte off

    const unsigned char* Abase = A + (size_t)(bm * 256) * KB;
    const unsigned char* Bbase = B + (size_t)(bn * 128) * KB;

    const int rsw = l16 & 7;

    #pragma unroll
    for (int k0 = 0; k0 < 2; ++k0) {              // 2 rounds of 128 B (=256 elems)
        const int sA = k0 ? 0x82828282 : 0x7F7F7F7F;   // 2^3 : 2^0
        const int sB = k0 ? 0x7C7C7C7C : 0x7F7F7F7F;   // 2^-3 : 2^0
        #pragma unroll
        for (int c = 0; c < 8; ++c) {             // A: 32 slabs of 8 rows
            int slab = wave * 8 + c;              // 0..31
            const unsigned char* ga = Abase + (size_t)(slab * 8 + st_row) * KB + k0 * 128 + st_k;
            __builtin_amdgcn_global_load_lds(
                (const __attribute__((address_space(1))) void*)ga,
                (__attribute__((address_space(3))) void*)(As + slab * 1024), 16, 0, 0);
        }
        #pragma unroll
        for (int c = 0; c < 4; ++c) {             // B: 16 slabs of 8 rows
            int slab = wave * 4 + c;              // 0..15
            const unsigned char* gb = Bbase + (size_t)(slab * 8 + st_row) * KB + k0 * 128 + st_k;
            __builtin_amdgcn_global_load_lds(
                (const __attribute__((address_space(1))) void*)gb,
                (__attribute__((address_space(3))) void*)(Bs + slab * 1024), 16, 0, 0);
        }
        __syncthreads();

        #pragma unroll
        for (int kh = 0; kh < 2; ++kh) {          // two K=128 MFMA windows
            // lane's 16-B chunk for this window: index kh*4+quad, XOR-swizzled
            const int sl = ((kh * 4 + quad) ^ rsw) * 16;
            i32x8v af[4];
            #pragma unroll
            for (int i = 0; i < 4; ++i) {
                i32x4v lo = *(const i32x4v*)(As + (wave_m + i * 16 + l16) * 128 + sl);
                i32x4v* h = (i32x4v*)&af[i];
                h[0] = lo; h[1] = lo;             // fp4 uses low 4 regs only
            }
            #pragma unroll
            for (int j = 0; j < 8; ++j) {
                i32x4v lo = *(const i32x4v*)(Bs + (j * 16 + l16) * 128 + sl);
                i32x8v bf;
                i32x4v* h = (i32x4v*)&bf;
                h[0] = lo; h[1] = lo;
                #pragma unroll
                for (int i = 0; i < 4; ++i)
                    acc[i][j] = __builtin_amdgcn_mfma_scale_f32_16x16x128_f8f6f4(
                        af[i], bf, acc[i][j],
                        4 /*cbsz: fp4 e2m1*/, 4 /*blgp: fp4 e2m1*/,
                        0, sA, 0, sB);
            }
        }
        __syncthreads();
    }

    // Epilogue: d2 -> exp -> *w -> reduce over this tile's 128 columns.
    // C/D layout (16x16 shapes): col = l16 (=n), row = quad*4 + reg (=m).
    float rowsum[4][4];
    #pragma unroll
    for (int i = 0; i < 4; ++i)
        #pragma unroll
        for (int r = 0; r < 4; ++r) rowsum[i][r] = 0.0f;

    const float NEG_LOG2E = -1.4426950408889634f;
    #pragma unroll
    for (int j = 0; j < 8; ++j) {
        int ng = bn * 128 + j * 16 + l16;
        float wj = w[ng];
        float cj = constc[ng];
        #pragma unroll
        for (int i = 0; i < 4; ++i)
            #pragma unroll
            for (int r = 0; r < 4; ++r) {
                float d2 = acc[i][j][r] + cj;
                rowsum[i][r] += exp2f(NEG_LOG2E * d2) * wj;
            }
    }

    #pragma unroll
    for (int mask = 1; mask < 16; mask <<= 1)
        #pragma unroll
        for (int i = 0; i < 4; ++i)
            #pragma unroll
            for (int r = 0; r < 4; ++r)
                rowsum[i][r] += __shfl_xor(rowsum[i][r], mask, 64);

    if (l16 == 0) {
        #pragma unroll
        for (int i = 0; i < 4; ++i)
            #pragma unroll
            for (int r = 0; r < 4; ++r) {
                int mg = bm * 256 + wave_m + i * 16 + quad * 4 + r;
                atomicAdd(&score[mg], rowsum[i][r]);
            }
    }
}

// ---------------------------------------------------------------------------
// finalize: out[n] = sigmoid(score[n] + b)
// ---------------------------------------------------------------------------
__global__ void finalize(const float* __restrict__ score,
                         const float* __restrict__ b,
                         float* __restrict__ out) {
    int n = blockIdx.x * 256 + threadIdx.x;
    if (n < MDIM) {
        float s = score[n] + b[0];
        out[n] = 1.0f / (1.0f + exp2f(-1.4426950408889634f * s));
    }
}

extern "C" void kernel_launch(void* const* d_in, const int* in_sizes, int n_in,
                              void* d_out, int out_size, void* d_ws, size_t ws_size,
                              hipStream_t stream) {
    const float* x       = (const float*)d_in[0];
    const float* centers = (const float*)d_in[1];
    const float* sigmas  = (const float*)d_in[2];
    const float* w_lin   = (const float*)d_in[3];
    const float* b_lin   = (const float*)d_in[4];
    float* out = (float*)d_out;

    char* ws = (char*)d_ws;
    unsigned char* Ap = (unsigned char*)ws;                       // 4 MB
    unsigned char* Bp = (unsigned char*)(ws + (size_t)MDIM * KB); // 1 MB
    float* cc    = (float*)(ws + (size_t)MDIM * KB + (size_t)CDIM * KB); // 16 KB
    float* score = (float*)((char*)cc + CDIM * sizeof(float));    // 64 KB

    prep<<<dim3(2048 + 512), dim3(256), 0, stream>>>(
        x, centers, sigmas, Ap, Bp, cc, score);
    gemm_fused<<<dim3(CDIM / 128, MDIM / 256), dim3(256), 0, stream>>>(
        Ap, Bp, cc, w_lin, score);
    finalize<<<dim3((MDIM + 255) / 256), dim3(256), 0, stream>>>(score, b_lin, out);
}

// Round 9
// 120.609 us; speedup vs baseline: 1.3343x; 1.0011x over previous
//
#include <hip/hip_runtime.h>
#include <cstdint>
#include <cstddef>

// Problem sizes (fixed by the reference)
#define MDIM 16384   // N_INPUT
#define CDIM 4096    // NUM_CENTERS
#define DDIM 256     // DIM
#define KDIM 512     // folded K elements; fp4 -> 256 bytes per row
#define KB   256     // row bytes (fp4)

typedef float f32x4  __attribute__((ext_vector_type(4)));
typedef int   i32x4v __attribute__((ext_vector_type(4)));
typedef int   i32x8v __attribute__((ext_vector_type(8)));

// e2m1 (OCP MXFP4) quantize, round-to-nearest: grid {0,.5,1,1.5,2,3,4,6}
__device__ __forceinline__ unsigned q4(float v) {
    unsigned s = (__builtin_bit_cast(unsigned, v) >> 31) << 3;
    float a = fabsf(v);
    unsigned c = (unsigned)(a >= 0.25f) + (a >= 0.75f) + (a >= 1.25f)
               + (a >= 1.75f) + (a >= 2.5f) + (a >= 3.5f) + (a >= 5.0f);
    return s | c;
}
__device__ __forceinline__ unsigned pack8(const float* v) {  // 8 vals -> 8 nibbles
    unsigned w = 0;
    #pragma unroll
    for (int i = 0; i < 8; ++i) w |= q4(v[i]) << (4 * i);
    return w;
}

// ---------------------------------------------------------------------------
// prep (fp4): A'[n] = [ x (256 fp4) | x^2/8 (256 fp4) ]       row = 256 B
//             B'[c] = [ -2*c*inv (256 fp4) | inv*8 (256 fp4) ]
//             constc[c] = sum_d c^2*inv (fp32).  Scales undone by MFMA E8M0.
// ---------------------------------------------------------------------------
__global__ __launch_bounds__(256) void prep(
    const float* __restrict__ x, const float* __restrict__ centers,
    const float* __restrict__ sigmas,
    unsigned char* __restrict__ Ap, unsigned char* __restrict__ Bp,
    float* __restrict__ constc, float* __restrict__ score) {
    int b = blockIdx.x, tid = threadIdx.x;
    if (b < 2048) {
        int idx8 = b * 256 + tid;                 // over MDIM*DDIM/8
        int n = idx8 >> 5, d8 = idx8 & 31;
        float v[8], v2[8];
        *(float4*)(v)     = ((const float4*)x)[idx8 * 2];
        *(float4*)(v + 4) = ((const float4*)x)[idx8 * 2 + 1];
        #pragma unroll
        for (int i = 0; i < 8; ++i) v2[i] = v[i] * v[i] * 0.125f;  // x^2/8
        *(unsigned*)(Ap + (size_t)n * KB + d8 * 4)       = pack8(v);
        *(unsigned*)(Ap + (size_t)n * KB + 128 + d8 * 4) = pack8(v2);
        if (idx8 < MDIM) score[idx8] = 0.0f;
    } else {
        int gid8 = (b - 2048) * 256 + tid;        // over CDIM*DDIM/8
        int c = gid8 >> 5, d8 = gid8 & 31;
        float cv[8], sv[8], cr[8], iv[8];
        *(float4*)(cv)     = ((const float4*)centers)[gid8 * 2];
        *(float4*)(cv + 4) = ((const float4*)centers)[gid8 * 2 + 1];
        *(float4*)(sv)     = ((const float4*)sigmas)[gid8 * 2];
        *(float4*)(sv + 4) = ((const float4*)sigmas)[gid8 * 2 + 1];
        float t = 0.0f;
        #pragma unroll
        for (int i = 0; i < 8; ++i) {
            float inv = 1.0f / (2.0f * sv[i] * sv[i]);
            cr[i] = -2.0f * cv[i] * inv;
            iv[i] = inv * 8.0f;                   // inv*8 (undone by 2^-3)
            t += cv[i] * cv[i] * inv;
        }
        *(unsigned*)(Bp + (size_t)c * KB + d8 * 4)       = pack8(cr);
        *(unsigned*)(Bp + (size_t)c * KB + 128 + d8 * 4) = pack8(iv);
        #pragma unroll
        for (int m = 16; m; m >>= 1) t += __shfl_xor(t, m, 64);  // 32-lane groups
        if ((tid & 31) == 0) constc[c] = t;
    }
}

// ---------------------------------------------------------------------------
// Fused MX-fp4 GEMM + exp + weighted C-reduction.
// d2 = A' B'^T + constc ; score[m] += sum_n exp(-d2[m][n]) * w[n]
// R8 = R7 skeleton (256x128 tile, 4 waves of 64Mx128N, 48 KB LDS, (256,2),
// XOR swizzle, BK=256 elems, cbsz=blgp=4, per-round E8M0 scales) with
// micro-fixes: undef-high fragment tuples (fp4 reads regs[0:3] only) and
// prefetched/pre-folded epilogue constants.
// ---------------------------------------------------------------------------
__global__ __launch_bounds__(256, 2) void gemm_fused(
    const unsigned char* __restrict__ A, const unsigned char* __restrict__ B,
    const float* __restrict__ constc, const float* __restrict__ w,
    float* __restrict__ score) {

    __shared__ unsigned char As[256 * 128];   // 32 KB
    __shared__ unsigned char Bs[128 * 128];   // 16 KB

    const int tid  = threadIdx.x;
    const int wave = tid >> 6;
    const int lane = tid & 63;
    const int quad = lane >> 4;      // 0..3
    const int l16  = lane & 15;

    const int bm = blockIdx.y;       // 0..63   (M blocks of 256)
    const int bn = blockIdx.x;       // 0..31   (C blocks of 128)

    const int wave_m = wave * 64;    // wave's 64 M-rows

    f32x4 acc[4][8] = {};

    // epilogue constants, prefetched so their L2 latency hides under the
    // K-loop. cjl = -log2(e)*constc folded for a single fma in the hot loop.
    const float NEG_LOG2E = -1.4426950408889634f;
    float wj8[8], cjl8[8];
    #pragma unroll
    for (int j = 0; j < 8; ++j) {
        int ng = bn * 128 + j * 16 + l16;
        wj8[j]  = w[ng];
        cjl8[j] = NEG_LOG2E * constc[ng];
    }

    // staging: one global_load_lds(16B)/lane stages 1024 B = 8 rows x 128 B.
    // lane -> row (lane>>3), slot (lane&7); fetch XOR-swizzled global chunk.
    const int st_row = lane >> 3;                     // 0..7
    const int st_k   = ((lane & 7) ^ st_row) * 16;    // swizzled global byte off

    const unsigned char* Abase = A + (size_t)(bm * 256) * KB;
    const unsigned char* Bbase = B + (size_t)(bn * 128) * KB;

    const int rsw = l16 & 7;

    #pragma unroll
    for (int k0 = 0; k0 < 2; ++k0) {              // 2 rounds of 128 B (=256 elems)
        const int sA = k0 ? 0x82828282 : 0x7F7F7F7F;   // 2^3 : 2^0
        const int sB = k0 ? 0x7C7C7C7C : 0x7F7F7F7F;   // 2^-3 : 2^0
        #pragma unroll
        for (int c = 0; c < 8; ++c) {             // A: 32 slabs of 8 rows
            int slab = wave * 8 + c;              // 0..31
            const unsigned char* ga = Abase + (size_t)(slab * 8 + st_row) * KB + k0 * 128 + st_k;
            __builtin_amdgcn_global_load_lds(
                (const __attribute__((address_space(1))) void*)ga,
                (__attribute__((address_space(3))) void*)(As + slab * 1024), 16, 0, 0);
        }
        #pragma unroll
        for (int c = 0; c < 4; ++c) {             // B: 16 slabs of 8 rows
            int slab = wave * 4 + c;              // 0..15
            const unsigned char* gb = Bbase + (size_t)(slab * 8 + st_row) * KB + k0 * 128 + st_k;
            __builtin_amdgcn_global_load_lds(
                (const __attribute__((address_space(1))) void*)gb,
                (__attribute__((address_space(3))) void*)(Bs + slab * 1024), 16, 0, 0);
        }
        __syncthreads();

        #pragma unroll
        for (int kh = 0; kh < 2; ++kh) {          // two K=128 MFMA windows
            // lane's 16-B chunk for this window: index kh*4+quad, XOR-swizzled
            const int sl = ((kh * 4 + quad) ^ rsw) * 16;
            i32x8v af[4];
            #pragma unroll
            for (int i = 0; i < 4; ++i) {
                i32x4v lo = *(const i32x4v*)(As + (wave_m + i * 16 + l16) * 128 + sl);
                af[i] = __builtin_shufflevector(lo, lo, 0, 1, 2, 3, -1, -1, -1, -1);
            }
            #pragma unroll
            for (int j = 0; j < 8; ++j) {
                i32x4v lo = *(const i32x4v*)(Bs + (j * 16 + l16) * 128 + sl);
                i32x8v bf = __builtin_shufflevector(lo, lo, 0, 1, 2, 3, -1, -1, -1, -1);
                #pragma unroll
                for (int i = 0; i < 4; ++i)
                    acc[i][j] = __builtin_amdgcn_mfma_scale_f32_16x16x128_f8f6f4(
                        af[i], bf, acc[i][j],
                        4 /*cbsz: fp4 e2m1*/, 4 /*blgp: fp4 e2m1*/,
                        0, sA, 0, sB);
            }
        }
        __syncthreads();
    }

    // Epilogue: rowsum[i][r] += exp2(d2*(-log2e) + cjl) * wj  (3 VALU/elem)
    // C/D layout (16x16 shapes): col = l16 (=n), row = quad*4 + reg (=m).
    float rowsum[4][4];
    #pragma unroll
    for (int i = 0; i < 4; ++i)
        #pragma unroll
        for (int r = 0; r < 4; ++r) rowsum[i][r] = 0.0f;

    #pragma unroll
    for (int j = 0; j < 8; ++j) {
        float wj  = wj8[j];
        float cjl = cjl8[j];
        #pragma unroll
        for (int i = 0; i < 4; ++i)
            #pragma unroll
            for (int r = 0; r < 4; ++r)
                rowsum[i][r] += exp2f(fmaf(acc[i][j][r], NEG_LOG2E, cjl)) * wj;
    }

    #pragma unroll
    for (int mask = 1; mask < 16; mask <<= 1)
        #pragma unroll
        for (int i = 0; i < 4; ++i)
            #pragma unroll
            for (int r = 0; r < 4; ++r)
                rowsum[i][r] += __shfl_xor(rowsum[i][r], mask, 64);

    if (l16 == 0) {
        #pragma unroll
        for (int i = 0; i < 4; ++i)
            #pragma unroll
            for (int r = 0; r < 4; ++r) {
                int mg = bm * 256 + wave_m + i * 16 + quad * 4 + r;
                atomicAdd(&score[mg], rowsum[i][r]);
            }
    }
}

// ---------------------------------------------------------------------------
// finalize: out[n] = sigmoid(score[n] + b)
// ---------------------------------------------------------------------------
__global__ void finalize(const float* __restrict__ score,
                         const float* __restrict__ b,
                         float* __restrict__ out) {
    int n = blockIdx.x * 256 + threadIdx.x;
    if (n < MDIM) {
        float s = score[n] + b[0];
        out[n] = 1.0f / (1.0f + exp2f(-1.4426950408889634f * s));
    }
}

extern "C" void kernel_launch(void* const* d_in, const int* in_sizes, int n_in,
                              void* d_out, int out_size, void* d_ws, size_t ws_size,
                              hipStream_t stream) {
    const float* x       = (const float*)d_in[0];
    const float* centers = (const float*)d_in[1];
    const float* sigmas  = (const float*)d_in[2];
    const float* w_lin   = (const float*)d_in[3];
    const float* b_lin   = (const float*)d_in[4];
    float* out = (float*)d_out;

    char* ws = (char*)d_ws;
    unsigned char* Ap = (unsigned char*)ws;                       // 4 MB
    unsigned char* Bp = (unsigned char*)(ws + (size_t)MDIM * KB); // 1 MB
    float* cc    = (float*)(ws + (size_t)MDIM * KB + (size_t)CDIM * KB); // 16 KB
    float* score = (float*)((char*)cc + CDIM * sizeof(float));    // 64 KB

    prep<<<dim3(2048 + 512), dim3(256), 0, stream>>>(
        x, centers, sigmas, Ap, Bp, cc, score);
    gemm_fused<<<dim3(CDIM / 128, MDIM / 256), dim3(256), 0, stream>>>(
        Ap, Bp, cc, w_lin, score);
    finalize<<<dim3((MDIM + 255) / 256), dim3(256), 0, stream>>>(score, b_lin, out);
}